// Round 1
// baseline (3316.803 us; speedup 1.0000x reference)
//
#include <hip/hip_runtime.h>
#include <hip/hip_bf16.h>
#include <math.h>

// Problem constants (from reference)
#define B_  4
#define S_  2048
#define DIN 1024
#define DM  1024
#define H_  16
#define DEPTH 64

// ---------------------------------------------------------------------------
// Tiled fp32 GEMM: C[M,N] = A[M,K] @ W[K,N] (+bias). Optionally writes the
// output in head-split layout [B, H, S, DEPTH] instead of [M, N].
// BM=BN=64, BK=16, 256 threads, 4x4 micro-tile per thread.
// ---------------------------------------------------------------------------
template<bool HEADSPLIT, bool BIAS>
__global__ __launch_bounds__(256)
void gemm_f32(const float* __restrict__ A, const float* __restrict__ W,
              const float* __restrict__ bias, float* __restrict__ C,
              int M, int N, int K) {
    __shared__ float sA[16][64];   // [k][m]
    __shared__ float sB[16][64];   // [k][n]
    const int t  = threadIdx.x;
    const int tx = t & 15;         // 0..15 -> n
    const int ty = t >> 4;         // 0..15 -> m
    const int m0 = blockIdx.y * 64;
    const int n0 = blockIdx.x * 64;

    // staging maps
    const int am = t >> 2;          // 0..63
    const int ak = (t & 3) << 2;    // 0,4,8,12
    const int wk = t >> 4;          // 0..15
    const int wn = (t & 15) << 2;   // 0..60

    float acc[4][4] = {};

    for (int k0 = 0; k0 < K; k0 += 16) {
        float4 a4 = *reinterpret_cast<const float4*>(&A[(size_t)(m0 + am) * K + k0 + ak]);
        float4 b4 = *reinterpret_cast<const float4*>(&W[(size_t)(k0 + wk) * N + n0 + wn]);
        __syncthreads();
        sA[ak + 0][am] = a4.x; sA[ak + 1][am] = a4.y;
        sA[ak + 2][am] = a4.z; sA[ak + 3][am] = a4.w;
        *reinterpret_cast<float4*>(&sB[wk][wn]) = b4;
        __syncthreads();
        #pragma unroll
        for (int kk = 0; kk < 16; ++kk) {
            float4 av = *reinterpret_cast<const float4*>(&sA[kk][ty * 4]);
            float4 bv = *reinterpret_cast<const float4*>(&sB[kk][tx * 4]);
            float a_[4] = {av.x, av.y, av.z, av.w};
            float b_[4] = {bv.x, bv.y, bv.z, bv.w};
            #pragma unroll
            for (int i = 0; i < 4; ++i)
                #pragma unroll
                for (int j = 0; j < 4; ++j)
                    acc[i][j] = fmaf(a_[i], b_[j], acc[i][j]);
        }
    }

    #pragma unroll
    for (int i = 0; i < 4; ++i) {
        const int row = m0 + ty * 4 + i;
        #pragma unroll
        for (int j = 0; j < 4; ++j) {
            const int col = n0 + tx * 4 + j;
            float v = acc[i][j];
            if (BIAS) v += bias[col];
            if (HEADSPLIT) {
                const int b = row / S_, s = row % S_;
                const int h = col / DEPTH, d = col % DEPTH;
                C[(((size_t)(b * H_ + h) * S_ + s) * DEPTH) + d] = v;
            } else {
                C[(size_t)row * N + col] = v;
            }
        }
    }
}

// ---------------------------------------------------------------------------
// Fused causal attention for 4 query rows per block (one wave per row).
// Computes logits into LDS, softmax (exact fp32, masked entries exactly 0
// like the reference's exp(-1e9) underflow), writes the attn row to d_out,
// then PV into ctx ([B, S, H*DEPTH] layout ready for the output projection).
// ---------------------------------------------------------------------------
#define QR 4
__global__ __launch_bounds__(256)
void attn_f32(const float* __restrict__ Qh, const float* __restrict__ Kh,
              const float* __restrict__ Vh, float* __restrict__ attn,
              float* __restrict__ ctx) {
    __shared__ float sL[QR][S_];       // 32 KB logits -> probs
    __shared__ float sKV[64][65];      // 16.6 KB staged K/V tile (padded)
    __shared__ float sQ[QR][DEPTH];    // 1 KB

    const int t    = threadIdx.x;
    const int qi   = t >> 6;           // wave id == local row
    const int lane = t & 63;
    const int q0   = blockIdx.x * QR;
    const size_t bh = (size_t)blockIdx.z * H_ + blockIdx.y;

    const float* Qb = Qh + bh * S_ * DEPTH;
    const float* Kb = Kh + bh * S_ * DEPTH;
    const float* Vb = Vh + bh * S_ * DEPTH;

    const int qabs = q0 + qi;
    const int kmaxblk = (q0 + QR - 1) >> 6;     // inclusive 64-wide k-block

    sQ[qi][lane] = Qb[(size_t)qabs * DEPTH + lane];
    __syncthreads();

    // ---- QK^T with causal mask ----
    for (int kb = 0; kb <= kmaxblk; ++kb) {
        const int k0 = kb * 64;
        #pragma unroll
        for (int i = 0; i < 16; ++i) {
            const int flat = i * 256 + t;
            const int r = flat >> 6, d = flat & 63;
            sKV[r][d] = Kb[(size_t)(k0 + r) * DEPTH + d];
        }
        __syncthreads();
        float acc = 0.f;
        #pragma unroll
        for (int d = 0; d < 64; ++d)
            acc = fmaf(sQ[qi][d], sKV[lane][d], acc);
        const int kabs = k0 + lane;
        sL[qi][kabs] = (kabs <= qabs) ? acc * 0.125f : -INFINITY;
        __syncthreads();
    }

    // ---- softmax (wave qi owns row qabs) ----
    float m = -INFINITY;
    for (int c = lane; c <= qabs; c += 64) m = fmaxf(m, sL[qi][c]);
    #pragma unroll
    for (int off = 1; off < 64; off <<= 1) m = fmaxf(m, __shfl_xor(m, off));

    const int nproc = (kmaxblk + 1) * 64;       // columns actually written
    float sum = 0.f;
    for (int c = lane; c < nproc; c += 64) {
        const float e = (c <= qabs) ? expf(sL[qi][c] - m) : 0.f;
        sL[qi][c] = e;
        sum += e;
    }
    #pragma unroll
    for (int off = 1; off < 64; off <<= 1) sum += __shfl_xor(sum, off);
    const float inv = 1.f / sum;

    // ---- write attn row (coalesced, exact zeros in masked region) ----
    float* arow = attn + (bh * S_ + qabs) * S_;
    for (int c = lane; c < S_; c += 64)
        arow[c] = (c < nproc) ? sL[qi][c] * inv : 0.f;

    // ---- PV: thread -> (row qi, dim lane) ----
    float acc = 0.f;
    for (int kb = 0; kb <= kmaxblk; ++kb) {
        const int k0 = kb * 64;
        __syncthreads();
        #pragma unroll
        for (int i = 0; i < 16; ++i) {
            const int flat = i * 256 + t;
            const int r = flat >> 6, d = flat & 63;
            sKV[r][d] = Vb[(size_t)(k0 + r) * DEPTH + d];
        }
        __syncthreads();
        #pragma unroll 8
        for (int r = 0; r < 64; ++r)
            acc = fmaf(sL[qi][k0 + r], sKV[r][lane], acc);
    }
    // ctx layout: [B, S, H*DEPTH] == concat layout for the output projection
    ctx[((size_t)blockIdx.z * S_ + qabs) * DM + blockIdx.y * DEPTH + lane] = acc * inv;
}

// ---------------------------------------------------------------------------
extern "C" void kernel_launch(void* const* d_in, const int* in_sizes, int n_in,
                              void* d_out, int out_size, void* d_ws, size_t ws_size,
                              hipStream_t stream) {
    const float* q  = (const float*)d_in[0];
    const float* k  = (const float*)d_in[1];
    const float* v  = (const float*)d_in[2];
    // d_in[3] is the causal mask; we apply causality analytically.
    const float* wq = (const float*)d_in[4];
    const float* wk = (const float*)d_in[5];
    const float* wv = (const float*)d_in[6];
    const float* wd = (const float*)d_in[7];
    const float* bd = (const float*)d_in[8];

    float* out  = (float*)d_out;                              // [B,S,DM]
    float* attn = (float*)d_out + (size_t)B_ * S_ * DM;       // [B,H,S,S]

    float* ws  = (float*)d_ws;
    float* Qh  = ws;                                          // [B,H,S,DEPTH]
    float* Kh  = Qh + (size_t)B_ * S_ * DM;
    float* Vh  = Kh + (size_t)B_ * S_ * DM;
    float* ctx = Vh + (size_t)B_ * S_ * DM;                   // [B,S,DM]

    const int M = B_ * S_;   // 8192

    dim3 gblk(256);
    dim3 ggrid(DM / 64, M / 64);   // (16, 128)
    hipLaunchKernelGGL((gemm_f32<true, false>), ggrid, gblk, 0, stream,
                       q, wq, nullptr, Qh, M, DM, DIN);
    hipLaunchKernelGGL((gemm_f32<true, false>), ggrid, gblk, 0, stream,
                       k, wk, nullptr, Kh, M, DM, DIN);
    hipLaunchKernelGGL((gemm_f32<true, false>), ggrid, gblk, 0, stream,
                       v, wv, nullptr, Vh, M, DM, DIN);

    dim3 agrid(S_ / QR, H_, B_);   // (512, 16, 4)
    hipLaunchKernelGGL(attn_f32, agrid, gblk, 0, stream, Qh, Kh, Vh, attn, ctx);

    hipLaunchKernelGGL((gemm_f32<false, true>), ggrid, gblk, 0, stream,
                       ctx, wd, bd, out, M, DM, DM);
}

// Round 2
// 1417.516 us; speedup vs baseline: 2.3399x; 2.3399x over previous
//
#include <hip/hip_runtime.h>
#include <hip/hip_bf16.h>
#include <math.h>

#define B_  4
#define S_  2048
#define DIN 1024
#define DM  1024
#define H_  16
#define DEPTH 64

typedef __attribute__((ext_vector_type(8))) short short8;
typedef __attribute__((ext_vector_type(4))) float f32x4;

// ---------------------------------------------------------------------------
// fp32 tiled GEMM. MODE 0: fp32 C[M][N] + bias. MODE 1: bf16 headsplit
// [b,h,s,d]. MODE 2: bf16 headsplit transposed [b,h,d,s] (for V).
// ---------------------------------------------------------------------------
template<int MODE>
__global__ __launch_bounds__(256)
void gemm_f32(const float* __restrict__ A, const float* __restrict__ W,
              const float* __restrict__ bias, float* __restrict__ Cf,
              __hip_bfloat16* __restrict__ Cb, int M, int N, int K) {
    __shared__ float sA[16][64];
    __shared__ float sB[16][64];
    const int t  = threadIdx.x;
    const int tx = t & 15, ty = t >> 4;
    const int m0 = blockIdx.y * 64, n0 = blockIdx.x * 64;
    const int am = t >> 2, ak = (t & 3) << 2;
    const int wk = t >> 4, wn = (t & 15) << 2;
    float acc[4][4] = {};
    for (int k0 = 0; k0 < K; k0 += 16) {
        float4 a4 = *reinterpret_cast<const float4*>(&A[(size_t)(m0 + am) * K + k0 + ak]);
        float4 b4 = *reinterpret_cast<const float4*>(&W[(size_t)(k0 + wk) * N + n0 + wn]);
        __syncthreads();
        sA[ak + 0][am] = a4.x; sA[ak + 1][am] = a4.y;
        sA[ak + 2][am] = a4.z; sA[ak + 3][am] = a4.w;
        *reinterpret_cast<float4*>(&sB[wk][wn]) = b4;
        __syncthreads();
        #pragma unroll
        for (int kk = 0; kk < 16; ++kk) {
            float4 av = *reinterpret_cast<const float4*>(&sA[kk][ty * 4]);
            float4 bv = *reinterpret_cast<const float4*>(&sB[kk][tx * 4]);
            float a_[4] = {av.x, av.y, av.z, av.w};
            float b_[4] = {bv.x, bv.y, bv.z, bv.w};
            #pragma unroll
            for (int i = 0; i < 4; ++i)
                #pragma unroll
                for (int j = 0; j < 4; ++j)
                    acc[i][j] = fmaf(a_[i], b_[j], acc[i][j]);
        }
    }
    #pragma unroll
    for (int i = 0; i < 4; ++i) {
        const int row = m0 + ty * 4 + i;
        #pragma unroll
        for (int j = 0; j < 4; ++j) {
            const int col = n0 + tx * 4 + j;
            float v = acc[i][j];
            if (MODE == 0) {
                Cf[(size_t)row * N + col] = v + bias[col];
            } else {
                const int bb = row >> 11, s = row & (S_ - 1);
                const int h  = col >> 6,  d = col & 63;
                if (MODE == 1)
                    Cb[(((size_t)(bb * H_ + h) * S_ + s) << 6) + d] = __float2bfloat16(v);
                else
                    Cb[((size_t)(bb * H_ + h) * DEPTH + d) * S_ + s] = __float2bfloat16(v);
            }
        }
    }
}

// ---------------------------------------------------------------------------
// bf16 MFMA causal attention. 64 q-rows per block, 4 waves (16 q-rows each).
// Two-pass: A = row sums of exp(logit/8); B = recompute, write attn, PV.
// LDS tiles row-major with chunk-XOR swizzle (c ^= row&7) -> conflict-free.
// ---------------------------------------------------------------------------
__device__ __forceinline__ void stage_tile(short* __restrict__ lds,
                                           const short* __restrict__ g,
                                           int rowstride, int t) {
    const int row = t >> 2;
    const int c0  = (t & 3) << 1;
    const short* src = g + (size_t)row * rowstride + (c0 << 3);
    short8 v0 = *reinterpret_cast<const short8*>(src);
    short8 v1 = *reinterpret_cast<const short8*>(src + 8);
    const int sw = row & 7;
    *reinterpret_cast<short8*>(lds + (((row << 3) + ((c0    ) ^ sw)) << 3)) = v0;
    *reinterpret_cast<short8*>(lds + (((row << 3) + ((c0 + 1) ^ sw)) << 3)) = v1;
}

__device__ __forceinline__ short8 ldfrag(const short* __restrict__ lds, int row, int c) {
    return *reinterpret_cast<const short8*>(lds + (((row << 3) + (c ^ (row & 7))) << 3));
}

__global__ __launch_bounds__(256)
void attn_mfma(const short* __restrict__ Qh, const short* __restrict__ Kh,
               const short* __restrict__ VhT, float* __restrict__ attn,
               float* __restrict__ ctx) {
    __shared__ __align__(16) short lQ[64 * 64];
    __shared__ __align__(16) short lK[64 * 64];
    __shared__ __align__(16) short lV[64 * 64];
    __shared__ __align__(16) short lP[4][16 * 64];

    const int t  = threadIdx.x;
    const int w  = t >> 6, l = t & 63;
    const int lg = l >> 4, lr = l & 15;
    const int qt = blockIdx.x, q0 = qt << 6;
    const int h  = blockIdx.y, b = blockIdx.z;
    const int bh = b * H_ + h;
    const float SC = 0.18033688f;   // log2(e)/8

    const short* Qg = Qh + ((((size_t)bh * S_) + q0) << 6);
    const short* Kg = Kh + (((size_t)bh * S_) << 6);
    const short* Vg = VhT + ((size_t)bh * DEPTH) * S_;

    // zero the strictly-upper (masked) attn region for our 64 rows
    {
        float4 z = make_float4(0.f, 0.f, 0.f, 0.f);
        float* rowp = attn + ((size_t)bh * S_ + q0 + (t >> 2)) * S_;
        for (int col = ((qt + 1) << 6) + ((t & 3) << 2); col < S_; col += 16)
            *reinterpret_cast<float4*>(rowp + col) = z;
    }

    stage_tile(lQ, Qg, 64, t);
    __syncthreads();

    const int qrow = w * 16 + lr;
    short8 aq0 = ldfrag(lQ, qrow, lg);
    short8 aq1 = ldfrag(lQ, qrow, lg + 4);

    // ---------------- pass A: row sums of exp ----------------
    float rsum[4] = {0.f, 0.f, 0.f, 0.f};
    for (int kb = 0; kb <= qt; ++kb) {
        __syncthreads();
        stage_tile(lK, Kg + ((size_t)kb << 12), 64, t);
        __syncthreads();
        f32x4 acc[4] = {};
        #pragma unroll
        for (int t4 = 0; t4 < 4; ++t4) {
            short8 bk0 = ldfrag(lK, t4 * 16 + lr, lg);
            short8 bk1 = ldfrag(lK, t4 * 16 + lr, lg + 4);
            acc[t4] = __builtin_amdgcn_mfma_f32_16x16x32_bf16(aq0, bk0, acc[t4], 0, 0, 0);
            acc[t4] = __builtin_amdgcn_mfma_f32_16x16x32_bf16(aq1, bk1, acc[t4], 0, 0, 0);
        }
        if (kb < qt) {
            #pragma unroll
            for (int t4 = 0; t4 < 4; ++t4)
                #pragma unroll
                for (int r = 0; r < 4; ++r)
                    rsum[r] += exp2f(acc[t4][r] * SC);
        } else {
            const int rl = w * 16 + lg * 4;
            #pragma unroll
            for (int t4 = 0; t4 < 4; ++t4) {
                const int cl = t4 * 16 + lr;
                #pragma unroll
                for (int r = 0; r < 4; ++r)
                    if (cl <= rl + r) rsum[r] += exp2f(acc[t4][r] * SC);
            }
        }
    }
    #pragma unroll
    for (int r = 0; r < 4; ++r) {
        #pragma unroll
        for (int m = 1; m < 16; m <<= 1) rsum[r] += __shfl_xor(rsum[r], m);
        rsum[r] = 1.f / rsum[r];   // now 1/sum
    }

    // ---------------- pass B: attn write + PV ----------------
    f32x4 ctxa[4] = {};
    short* lPw = lP[w];
    for (int kb = 0; kb <= qt; ++kb) {
        __syncthreads();
        stage_tile(lK, Kg + ((size_t)kb << 12), 64, t);
        stage_tile(lV, Vg + (kb << 6), S_, t);
        __syncthreads();
        f32x4 acc[4] = {};
        #pragma unroll
        for (int t4 = 0; t4 < 4; ++t4) {
            short8 bk0 = ldfrag(lK, t4 * 16 + lr, lg);
            short8 bk1 = ldfrag(lK, t4 * 16 + lr, lg + 4);
            acc[t4] = __builtin_amdgcn_mfma_f32_16x16x32_bf16(aq0, bk0, acc[t4], 0, 0, 0);
            acc[t4] = __builtin_amdgcn_mfma_f32_16x16x32_bf16(aq1, bk1, acc[t4], 0, 0, 0);
        }
        const bool diag = (kb == qt);
        float* abase = attn + ((size_t)bh * S_ + q0 + w * 16 + lg * 4) * S_ + ((size_t)kb << 6);
        #pragma unroll
        for (int t4 = 0; t4 < 4; ++t4) {
            const int cl = t4 * 16 + lr;
            #pragma unroll
            for (int r = 0; r < 4; ++r) {
                float p;
                if (diag && cl > w * 16 + lg * 4 + r) p = 0.f;
                else p = exp2f(acc[t4][r] * SC) * rsum[r];
                abase[(size_t)r * S_ + cl] = p;
                __hip_bfloat16 hb = __float2bfloat16(p);
                short sv; __builtin_memcpy(&sv, &hb, 2);
                const int prow = lg * 4 + r;
                lPw[(prow << 6) + (((t4 * 2 + (lr >> 3)) ^ (prow & 7)) << 3) + (lr & 7)] = sv;
            }
        }
        short8 pa0 = ldfrag(lPw, lr, lg);
        short8 pa1 = ldfrag(lPw, lr, lg + 4);
        #pragma unroll
        for (int td = 0; td < 4; ++td) {
            short8 v0 = ldfrag(lV, td * 16 + lr, lg);
            short8 v1 = ldfrag(lV, td * 16 + lr, lg + 4);
            ctxa[td] = __builtin_amdgcn_mfma_f32_16x16x32_bf16(pa0, v0, ctxa[td], 0, 0, 0);
            ctxa[td] = __builtin_amdgcn_mfma_f32_16x16x32_bf16(pa1, v1, ctxa[td], 0, 0, 0);
        }
    }

    float* cbase = ctx + ((size_t)(b * S_) + q0 + w * 16 + lg * 4) * DM + h * 64;
    #pragma unroll
    for (int td = 0; td < 4; ++td)
        #pragma unroll
        for (int r = 0; r < 4; ++r)
            cbase[(size_t)r * DM + td * 16 + lr] = ctxa[td][r];
}

// ---------------------------------------------------------------------------
extern "C" void kernel_launch(void* const* d_in, const int* in_sizes, int n_in,
                              void* d_out, int out_size, void* d_ws, size_t ws_size,
                              hipStream_t stream) {
    const float* q  = (const float*)d_in[0];
    const float* k  = (const float*)d_in[1];
    const float* v  = (const float*)d_in[2];
    // d_in[3]: causal mask, applied analytically
    const float* wq = (const float*)d_in[4];
    const float* wk = (const float*)d_in[5];
    const float* wv = (const float*)d_in[6];
    const float* wd = (const float*)d_in[7];
    const float* bd = (const float*)d_in[8];

    float* out  = (float*)d_out;
    float* attn = (float*)d_out + (size_t)B_ * S_ * DM;

    char* wsc = (char*)d_ws;
    __hip_bfloat16* Qh  = (__hip_bfloat16*)(wsc);                       // 16 MB
    __hip_bfloat16* Kh  = (__hip_bfloat16*)(wsc + (size_t)(16 << 20));  // 16 MB
    __hip_bfloat16* VhT = (__hip_bfloat16*)(wsc + (size_t)(32 << 20));  // 16 MB
    float*          ctx = (float*)(wsc + (size_t)(48 << 20));           // 32 MB

    const int M = B_ * S_;
    dim3 blk(256);
    dim3 gg(DM / 64, M / 64);

    hipLaunchKernelGGL((gemm_f32<1>), gg, blk, 0, stream, q, wq, nullptr, nullptr, Qh, M, DM, DIN);
    hipLaunchKernelGGL((gemm_f32<1>), gg, blk, 0, stream, k, wk, nullptr, nullptr, Kh, M, DM, DIN);
    hipLaunchKernelGGL((gemm_f32<2>), gg, blk, 0, stream, v, wv, nullptr, nullptr, VhT, M, DM, DIN);

    hipLaunchKernelGGL(attn_mfma, dim3(S_ / 64, H_, B_), blk, 0, stream,
                       (const short*)Qh, (const short*)Kh, (const short*)VhT, attn, ctx);

    hipLaunchKernelGGL((gemm_f32<0>), gg, blk, 0, stream, ctx, wd, bd, out, nullptr, M, DM, DM);
}

// Round 4
// 624.125 us; speedup vs baseline: 5.3143x; 2.2712x over previous
//
// Round 3: identical resubmission of round-2 kernel (bench infra failure,
// no counters returned — re-running to get the measurement).
#include <hip/hip_runtime.h>
#include <hip/hip_bf16.h>
#include <math.h>

#define B_  4
#define S_  2048
#define DM  1024
#define H_  16

typedef __attribute__((ext_vector_type(8))) short short8;
typedef __attribute__((ext_vector_type(4))) short short4v;
typedef __attribute__((ext_vector_type(4))) float f32x4;

__device__ __forceinline__ short bf16b(float f) {
    __hip_bfloat16 h = __float2bfloat16(f);
    short s; __builtin_memcpy(&s, &h, 2);
    return s;
}

// LDS tile convention: [row][8 chunks of 8 shorts], chunk c stored at slot
// c ^ (row & 7). ldfrag(row, c) returns global chunk c (k-offset c*8).
__device__ __forceinline__ short8 ldfrag(const short* __restrict__ lds, int row, int c) {
    return *reinterpret_cast<const short8*>(lds + (((row << 3) + (c ^ (row & 7))) << 3));
}

// ---------------------------------------------------------------------------
// fp32 -> bf16 flat cast (8 elements / thread)
// ---------------------------------------------------------------------------
__global__ __launch_bounds__(256)
void cast_bf16(const float* __restrict__ in, short* __restrict__ out, int n8) {
    int i = blockIdx.x * 256 + threadIdx.x;
    if (i >= n8) return;
    const float4* p = reinterpret_cast<const float4*>(in) + (size_t)i * 2;
    float4 a = p[0], b = p[1];
    short8 o;
    o[0] = bf16b(a.x); o[1] = bf16b(a.y); o[2] = bf16b(a.z); o[3] = bf16b(a.w);
    o[4] = bf16b(b.x); o[5] = bf16b(b.y); o[6] = bf16b(b.z); o[7] = bf16b(b.w);
    reinterpret_cast<short8*>(out)[i] = o;
}

// ---------------------------------------------------------------------------
// W fp32 [K][N] -> WT bf16 [N][K]  (1024x1024)
// ---------------------------------------------------------------------------
__global__ __launch_bounds__(256)
void tcast(const float* __restrict__ W, short* __restrict__ WT) {
    __shared__ float tile[64][65];
    const int n0 = blockIdx.x << 6, k0 = blockIdx.y << 6;
    const int t = threadIdx.x;
    #pragma unroll
    for (int i = 0; i < 16; ++i) {
        int f = i * 256 + t, r = f >> 6, c = f & 63;
        tile[r][c] = W[(size_t)(k0 + r) * DM + n0 + c];
    }
    __syncthreads();
    #pragma unroll
    for (int i = 0; i < 16; ++i) {
        int f = i * 256 + t, r = f >> 6, c = f & 63;
        WT[(size_t)(n0 + r) * DM + k0 + c] = bf16b(tile[c][r]);
    }
}

// ---------------------------------------------------------------------------
// bf16 MFMA GEMM: C[8192,1024] = A[8192,1024] @ BT[1024,1024]^T, K=1024.
// 128x128 tile, BK=64, 4 waves (2x2 of 64x64), swizzled LDS, prefetch.
// EPI 0: bf16 headsplit [b,h,s,d]; EPI 1: bf16 headsplit-T [b,h,d,s];
// EPI 2: fp32 [M,N] + bias.
// ---------------------------------------------------------------------------
template<int EPI>
__global__ __launch_bounds__(256)
void gemm_nt(const short* __restrict__ A, const short* __restrict__ BT,
             const float* __restrict__ bias, short* __restrict__ Cb,
             float* __restrict__ Cf) {
    __shared__ __align__(16) short lA[128 * 64];
    __shared__ __align__(16) short lB[128 * 64];
    const int K = 1024;
    const int id = blockIdx.x;
    const int swz = ((id & 7) << 6) + (id >> 3);   // XCD-aware, 512 % 8 == 0
    const int bm = swz >> 3, bn = swz & 7;
    const int t = threadIdx.x, w = t >> 6, l = t & 63, lg = l >> 4, lr = l & 15;
    const int wm = w >> 1, wn = w & 1;

    // staging map: thread -> row t>>1, chunks {(t&1) + 2j}, j=0..3
    const int srow = t >> 1, sw = srow & 7, codd = t & 1;
    const short* Ab = A  + (size_t)(bm * 128 + srow) * K + (codd << 3);
    const short* Bb = BT + (size_t)(bn * 128 + srow) * K + (codd << 3);
    short* la = lA + (srow << 6);
    short* lb = lB + (srow << 6);

    f32x4 acc[4][4] = {};
    short8 va[4], vb[4];
    #pragma unroll
    for (int j = 0; j < 4; ++j) {
        va[j] = *reinterpret_cast<const short8*>(Ab + (j << 4));
        vb[j] = *reinterpret_cast<const short8*>(Bb + (j << 4));
    }

    for (int k0 = 0; k0 < K; k0 += 64) {
        __syncthreads();
        #pragma unroll
        for (int j = 0; j < 4; ++j) {
            const int c = (codd + (j << 1)) ^ sw;
            *reinterpret_cast<short8*>(la + (c << 3)) = va[j];
            *reinterpret_cast<short8*>(lb + (c << 3)) = vb[j];
        }
        __syncthreads();
        if (k0 + 64 < K) {
            #pragma unroll
            for (int j = 0; j < 4; ++j) {
                va[j] = *reinterpret_cast<const short8*>(Ab + k0 + 64 + (j << 4));
                vb[j] = *reinterpret_cast<const short8*>(Bb + k0 + 64 + (j << 4));
            }
        }
        #pragma unroll
        for (int kk = 0; kk < 2; ++kk) {
            short8 af[4], bfr[4];
            #pragma unroll
            for (int fm = 0; fm < 4; ++fm) af[fm]  = ldfrag(lA, wm * 64 + fm * 16 + lr, kk * 4 + lg);
            #pragma unroll
            for (int fn = 0; fn < 4; ++fn) bfr[fn] = ldfrag(lB, wn * 64 + fn * 16 + lr, kk * 4 + lg);
            #pragma unroll
            for (int fm = 0; fm < 4; ++fm)
                #pragma unroll
                for (int fn = 0; fn < 4; ++fn)
                    acc[fm][fn] = __builtin_amdgcn_mfma_f32_16x16x32_bf16(af[fm], bfr[fn], acc[fm][fn], 0, 0, 0);
        }
    }

    const int rb = bm * 128 + wm * 64 + ((l >> 4) << 2);
    const int cb = bn * 128 + wn * 64 + lr;
    #pragma unroll
    for (int fm = 0; fm < 4; ++fm) {
        #pragma unroll
        for (int fn = 0; fn < 4; ++fn) {
            const int col = cb + fn * 16;
            if (EPI == 2) {
                const float bv = bias[col];
                #pragma unroll
                for (int r = 0; r < 4; ++r) {
                    const int row = rb + fm * 16 + r;
                    Cf[(size_t)row * DM + col] = acc[fm][fn][r] + bv;
                }
            } else if (EPI == 0) {
                const int h = col >> 6, d = col & 63;
                #pragma unroll
                for (int r = 0; r < 4; ++r) {
                    const int row = rb + fm * 16 + r;
                    const int b = row >> 11, s = row & 2047;
                    Cb[(((size_t)(b * H_ + h) * S_ + s) << 6) + d] = bf16b(acc[fm][fn][r]);
                }
            } else {
                const int h = col >> 6, d = col & 63;
                const int row0 = rb + fm * 16;
                const int b = row0 >> 11, s = row0 & 2047;
                short4v pk;
                #pragma unroll
                for (int r = 0; r < 4; ++r) pk[r] = bf16b(acc[fm][fn][r]);
                *reinterpret_cast<short4v*>(Cb + (((size_t)(b * H_ + h) << 6) + d) * S_ + s) = pk;
            }
        }
    }
}

// ---------------------------------------------------------------------------
// bf16 MFMA causal attention. 128 q-rows/block, 8 waves (16 rows each).
// Two-pass: A = row sums of exp(logit); B = recompute, write attn fp32, PV.
// ctx written bf16 [B*S, DM]. Per-wave causal tile skip.
// ---------------------------------------------------------------------------
__global__ __launch_bounds__(512, 4)
void attn_mfma(const short* __restrict__ Qh, const short* __restrict__ Kh,
               const short* __restrict__ VhT, float* __restrict__ attn,
               short* __restrict__ ctxb) {
    __shared__ __align__(16) short lQ[128 * 64];
    __shared__ __align__(16) short lK[64 * 64];
    __shared__ __align__(16) short lV[64 * 64];
    __shared__ __align__(16) short lP[8][16 * 64];

    const int t = threadIdx.x, w = t >> 6, l = t & 63, lg = l >> 4, lr = l & 15;
    const int qt = blockIdx.x, q0 = qt << 7;
    const int h = blockIdx.y, b = blockIdx.z, bh = b * H_ + h;
    const float SC = 0.18033688f;   // log2(e)/8

    const short* Qg = Qh  + (((size_t)bh * S_ + q0) << 6);
    const short* Kg = Kh  + ((size_t)bh * S_ << 6);
    const short* Vg = VhT + ((size_t)bh << 6) * S_;

    const int wrow = w * 16;
    const int Kw   = (q0 + wrow + 15) >> 6;   // last tile this wave computes
    const int nkb  = (q0 + 128) >> 6;         // tiles staged by the block

    // zero-fill the never-computed tail of this wave's 16 rows
    {
        const int zs = (Kw + 1) << 6;
        float* rowp = attn + ((size_t)bh * S_ + q0 + wrow + (l >> 2)) * S_;
        const float4 z = make_float4(0.f, 0.f, 0.f, 0.f);
        for (int c = zs + ((l & 3) << 2); c < S_; c += 16)
            *reinterpret_cast<float4*>(rowp + c) = z;
    }

    // stage Q (128 rows x 8 chunks, 2 chunks/thread)
    {
        const int row = t >> 2, c0 = (t & 3) << 1, sw = row & 7;
        const short* src = Qg + ((size_t)row << 6) + (c0 << 3);
        short8 v0 = *reinterpret_cast<const short8*>(src);
        short8 v1 = *reinterpret_cast<const short8*>(src + 8);
        *reinterpret_cast<short8*>(lQ + (((row << 3) + ((c0    ) ^ sw)) << 3)) = v0;
        *reinterpret_cast<short8*>(lQ + (((row << 3) + ((c0 + 1) ^ sw)) << 3)) = v1;
    }
    __syncthreads();

    const int qrow = wrow + lr;
    short8 aq0 = ldfrag(lQ, qrow, lg);
    short8 aq1 = ldfrag(lQ, qrow, lg + 4);
    const int rloc = q0 + wrow + (lg << 2);   // abs row of acc reg 0

    // ---------------- pass A: row sums ----------------
    float rsum[4] = {0.f, 0.f, 0.f, 0.f};
    for (int kb = 0; kb < nkb; ++kb) {
        __syncthreads();
        {
            const int row = t >> 3, c = t & 7;
            short8 v = *reinterpret_cast<const short8*>(Kg + (((size_t)(kb * 64 + row)) << 6) + (c << 3));
            *reinterpret_cast<short8*>(lK + (((row << 3) + (c ^ (row & 7))) << 3)) = v;
        }
        __syncthreads();
        if (kb * 64 > q0 + wrow + 15) continue;
        f32x4 acc[4] = {};
        #pragma unroll
        for (int t4 = 0; t4 < 4; ++t4) {
            short8 bk0 = ldfrag(lK, t4 * 16 + lr, lg);
            short8 bk1 = ldfrag(lK, t4 * 16 + lr, lg + 4);
            acc[t4] = __builtin_amdgcn_mfma_f32_16x16x32_bf16(aq0, bk0, acc[t4], 0, 0, 0);
            acc[t4] = __builtin_amdgcn_mfma_f32_16x16x32_bf16(aq1, bk1, acc[t4], 0, 0, 0);
        }
        if (kb * 64 + 63 <= q0 + wrow) {
            #pragma unroll
            for (int t4 = 0; t4 < 4; ++t4)
                #pragma unroll
                for (int r = 0; r < 4; ++r)
                    rsum[r] += exp2f(acc[t4][r] * SC);
        } else {
            #pragma unroll
            for (int t4 = 0; t4 < 4; ++t4) {
                const int cabs = kb * 64 + t4 * 16 + lr;
                #pragma unroll
                for (int r = 0; r < 4; ++r)
                    if (cabs <= rloc + r) rsum[r] += exp2f(acc[t4][r] * SC);
            }
        }
    }
    #pragma unroll
    for (int r = 0; r < 4; ++r) {
        #pragma unroll
        for (int m = 1; m < 16; m <<= 1) rsum[r] += __shfl_xor(rsum[r], m);
        rsum[r] = 1.f / rsum[r];
    }

    // ---------------- pass B: attn write + PV ----------------
    f32x4 ctxa[4] = {};
    short* lPw = lP[w];
    for (int kb = 0; kb < nkb; ++kb) {
        __syncthreads();
        {
            const int row = t >> 3, c = t & 7;
            short8 vk = *reinterpret_cast<const short8*>(Kg + (((size_t)(kb * 64 + row)) << 6) + (c << 3));
            short8 vv = *reinterpret_cast<const short8*>(Vg + (size_t)row * S_ + kb * 64 + (c << 3));
            *reinterpret_cast<short8*>(lK + (((row << 3) + (c ^ (row & 7))) << 3)) = vk;
            *reinterpret_cast<short8*>(lV + (((row << 3) + (c ^ (row & 7))) << 3)) = vv;
        }
        __syncthreads();
        if (kb * 64 > q0 + wrow + 15) continue;
        f32x4 acc[4] = {};
        #pragma unroll
        for (int t4 = 0; t4 < 4; ++t4) {
            short8 bk0 = ldfrag(lK, t4 * 16 + lr, lg);
            short8 bk1 = ldfrag(lK, t4 * 16 + lr, lg + 4);
            acc[t4] = __builtin_amdgcn_mfma_f32_16x16x32_bf16(aq0, bk0, acc[t4], 0, 0, 0);
            acc[t4] = __builtin_amdgcn_mfma_f32_16x16x32_bf16(aq1, bk1, acc[t4], 0, 0, 0);
        }
        const bool fullt = (kb * 64 + 63 <= q0 + wrow);
        float* abase = attn + ((size_t)bh * S_ + rloc) * S_ + kb * 64;
        #pragma unroll
        for (int t4 = 0; t4 < 4; ++t4) {
            const int cl = t4 * 16 + lr;
            const int cabs = kb * 64 + cl;
            #pragma unroll
            for (int r = 0; r < 4; ++r) {
                float p;
                if (!fullt && cabs > rloc + r) p = 0.f;
                else p = exp2f(acc[t4][r] * SC) * rsum[r];
                abase[(size_t)r * S_ + cl] = p;
                const int prow = (lg << 2) + r;
                lPw[(prow << 6) + (((t4 * 2 + (lr >> 3)) ^ (prow & 7)) << 3) + (l & 7)] = bf16b(p);
            }
        }
        short8 pa0 = ldfrag(lPw, lr, lg);
        short8 pa1 = ldfrag(lPw, lr, lg + 4);
        #pragma unroll
        for (int td = 0; td < 4; ++td) {
            short8 v0 = ldfrag(lV, td * 16 + lr, lg);
            short8 v1 = ldfrag(lV, td * 16 + lr, lg + 4);
            ctxa[td] = __builtin_amdgcn_mfma_f32_16x16x32_bf16(pa0, v0, ctxa[td], 0, 0, 0);
            ctxa[td] = __builtin_amdgcn_mfma_f32_16x16x32_bf16(pa1, v1, ctxa[td], 0, 0, 0);
        }
    }

    short* cbase = ctxb + ((size_t)(b * S_) + q0 + wrow + (lg << 2)) * DM + (h << 6);
    #pragma unroll
    for (int td = 0; td < 4; ++td)
        #pragma unroll
        for (int r = 0; r < 4; ++r)
            cbase[(size_t)r * DM + td * 16 + lr] = bf16b(ctxa[td][r]);
}

// ---------------------------------------------------------------------------
extern "C" void kernel_launch(void* const* d_in, const int* in_sizes, int n_in,
                              void* d_out, int out_size, void* d_ws, size_t ws_size,
                              hipStream_t stream) {
    const float* q  = (const float*)d_in[0];
    const float* k  = (const float*)d_in[1];
    const float* v  = (const float*)d_in[2];
    // d_in[3]: causal mask, applied analytically
    const float* wq = (const float*)d_in[4];
    const float* wk = (const float*)d_in[5];
    const float* wv = (const float*)d_in[6];
    const float* wd = (const float*)d_in[7];
    const float* bd = (const float*)d_in[8];

    float* out  = (float*)d_out;
    float* attn = (float*)d_out + (size_t)B_ * S_ * DM;

    char* wsc = (char*)d_ws;
    short* castb = (short*)wsc;                                  // 16 MB (qb/kb/vb/ctx)
    short* wT0 = (short*)(wsc + ((size_t)16 << 20));             // 2 MB each
    short* wT1 = (short*)(wsc + ((size_t)18 << 20));
    short* wT2 = (short*)(wsc + ((size_t)20 << 20));
    short* wT3 = (short*)(wsc + ((size_t)22 << 20));
    short* Qh  = (short*)(wsc + ((size_t)24 << 20));             // 16 MB
    short* Kh  = (short*)(wsc + ((size_t)40 << 20));             // 16 MB
    short* VhT = (short*)(wsc + ((size_t)56 << 20));             // 16 MB

    const dim3 b256(256);
    const dim3 tg(16, 16);
    hipLaunchKernelGGL(tcast, tg, b256, 0, stream, wq, wT0);
    hipLaunchKernelGGL(tcast, tg, b256, 0, stream, wk, wT1);
    hipLaunchKernelGGL(tcast, tg, b256, 0, stream, wv, wT2);
    hipLaunchKernelGGL(tcast, tg, b256, 0, stream, wd, wT3);

    const int n8 = (B_ * S_ * DM) / 8;   // 1,048,576
    const dim3 cg(n8 / 256);

    hipLaunchKernelGGL(cast_bf16, cg, b256, 0, stream, q, castb, n8);
    hipLaunchKernelGGL((gemm_nt<0>), dim3(512), b256, 0, stream, castb, wT0, nullptr, Qh, nullptr);
    hipLaunchKernelGGL(cast_bf16, cg, b256, 0, stream, k, castb, n8);
    hipLaunchKernelGGL((gemm_nt<0>), dim3(512), b256, 0, stream, castb, wT1, nullptr, Kh, nullptr);
    hipLaunchKernelGGL(cast_bf16, cg, b256, 0, stream, v, castb, n8);
    hipLaunchKernelGGL((gemm_nt<1>), dim3(512), b256, 0, stream, castb, wT2, nullptr, VhT, nullptr);

    hipLaunchKernelGGL(attn_mfma, dim3(16, 16, 4), dim3(512), 0, stream,
                       Qh, Kh, VhT, attn, castb);

    hipLaunchKernelGGL((gemm_nt<2>), dim3(512), b256, 0, stream, castb, wT3, bd, nullptr, out);
}